// Round 1
// baseline (431.141 us; speedup 1.0000x reference)
//
#include <hip/hip_runtime.h>
#include <math.h>

#define NPTS  16384
#define KNN   16
#define SEQV  8
#define NW    16      // waves per block
#define SLICE 1024    // candidates per wave slice
#define BATCH 8
#define CAPM  15      // append words/thread (flush thr 7 -> max idx 14, storm-free)

// Transposed LDS slot: row t (0..15), column col (0..1023).
// bank = col mod 32 -> consecutive lanes = consecutive banks = conflict-free.
#define SLOT(arr, t, col) arr[(t) * 1024 + (col)]

__device__ __forceinline__ unsigned umin_(unsigned a, unsigned b) { return a < b ? a : b; }
__device__ __forceinline__ unsigned umax_(unsigned a, unsigned b) { return a > b ? a : b; }

// merge one key into sorted ascending keys[16]
__device__ __forceinline__ void merge_one(unsigned keys[KNN], unsigned kk) {
    if (kk < keys[KNN - 1]) {
#pragma unroll
        for (int u = 0; u < KNN; ++u) {
            unsigned lo = umin_(kk, keys[u]);
            kk = umax_(kk, keys[u]);
            keys[u] = lo;
        }
    }
}

// ---------------------------------------------------------------------------
// K0: pack pc4[i] = (-2x, -2y, -2z, |c|^2); zero accumulators.
// The -2 folding turns the scan's per-candidate d2p into a pure 3-fma chain:
//   d2p = d2 - |q|^2 = m.x*qx + m.y*qy + m.z*qz + m.w
// Query recovered bit-exactly as q = -0.5 * m (power-of-2 scale).
// ---------------------------------------------------------------------------
__global__ __launch_bounds__(256) void pack_kernel(
    const float* __restrict__ pc, float4* __restrict__ pc4,
    float* __restrict__ accum)
{
    const int i = blockIdx.x * 256 + threadIdx.x;
    if (i == 0) {
        accum[0] = 0.0f; accum[1] = 0.0f;
        ((unsigned*)accum)[2] = 0u; ((unsigned*)accum)[3] = 0u;
    }
    const float x = pc[3 * i + 0];
    const float y = pc[3 * i + 1];
    const float z = pc[3 * i + 2];
    const float w = fmaf(x, x, fmaf(y, y, z * z));
    pc4[i] = make_float4(-2.0f * x, -2.0f * y, -2.0f * z, w);
}

// ---------------------------------------------------------------------------
// K1: self-tau mega. Grid 256 x 1024. Each block owns 64 queries (lane =
// query); each of 16 waves scans its own 1024-candidate slice with a
// PROGRESSIVE filter seeded at +inf and tightened from the wave's own
// keys[15] at every flush (same margin logic as before -> each wave ends
// with the EXACT top-16 of its slice; tree merge -> exact global top-16).
// This replaces the entire 111-us sample_tau pre-pass, whose only output
// was a starting tau worth ~18 fewer merges/lane.
// key = (d2 bits & 0xFFFFC000) | j  (j < 2^14).
// accum[0]=loss, accum[1]=wsum, accum[2]=ticket (zeroed by K0).
// ---------------------------------------------------------------------------
__global__ __launch_bounds__(1024, 4) void mega_kernel(
    const float4* __restrict__ pc4, const float* __restrict__ flow,
    const float* __restrict__ wts, float* __restrict__ accum,
    float* __restrict__ out)
{
    __shared__ unsigned uS[1024 * 16];   // 64 KB union: scan bufs / merge / ids
    float* sred = (float*)&uS[15 * 1024 + 1000];

    const int tid  = threadIdx.x;
    const int lane = tid & 63;
    const int wv   = __builtin_amdgcn_readfirstlane(tid >> 6);   // 0..15
    const int i    = blockIdx.x * 64 + lane;

    const float4 mi = pc4[i];
    const float qx = -0.5f * mi.x;      // exact: power-of-2 rescale
    const float qy = -0.5f * mi.y;
    const float qz = -0.5f * mi.z;
    const float q2 = mi.w;
    float tauf = 3.0e38f;               // self-tau: starts open, tightens

    unsigned keys[KNN];
#pragma unroll
    for (int t = 0; t < KNN; ++t) keys[t] = 0xFFFFFFFFu;
    int cnt = 0;
    unsigned* buf = &uS[tid * CAPM];     // stride 15 (odd) -> spread banks

    const int jbeg = wv * SLICE;
    const float4* cb = pc4 + jbeg;       // wave-uniform -> s_load bursts

    // ================= Phase A: self-filtered scan ========================
    {
        float4 A[BATCH], B[BATCH];
#pragma unroll
        for (int q = 0; q < BATCH; ++q) A[q] = cb[q];

        auto process = [&](const float4* C, int jbase) {
#pragma unroll
            for (int q = 0; q < BATCH; ++q) {
                const float4 c = C[q];
                float d2p = fmaf(c.x, qx, fmaf(c.y, qy, fmaf(c.z, qz, c.w)));
                if (d2p <= tauf) {                     // exec-masked accept
                    float d2 = fmaxf(d2p + q2, 0.0f);
                    buf[cnt] = (__float_as_uint(d2) & 0xFFFFC000u)
                             | (unsigned)(jbeg + jbase + q);
                    ++cnt;
                }
            }
            // headroom: enter batch with cnt <= 6 -> max idx 14 = CAPM-1
            if (cnt >= CAPM - BATCH) {
#pragma unroll 1
                for (int t = 0; t < cnt; ++t) merge_one(keys, buf[t]);
                cnt = 0;
                // sentinel keys[15] -> NaN d16 -> fminf keeps old tauf
                float d16n = __uint_as_float(keys[KNN - 1] & 0xFFFFC000u);
                tauf = fminf(tauf, fmaf(d16n, 1.0002f, 1e-6f) - q2);
            }
        };

#pragma unroll 1
        for (int jo = 0; jo < SLICE; jo += 2 * BATCH) {
#pragma unroll
            for (int q = 0; q < BATCH; ++q) B[q] = cb[jo + BATCH + q];
            process(A, jo);
            if (jo + 2 * BATCH < SLICE) {
#pragma unroll
                for (int q = 0; q < BATCH; ++q) A[q] = cb[jo + 2 * BATCH + q];
            }
            process(B, jo + BATCH);
        }
#pragma unroll 1
        for (int t = 0; t < cnt; ++t) merge_one(keys, buf[t]);
    }
    __syncthreads();   // scan buffers dead; reuse uS as transposed merge slots

    // ================= Phase B: tree merge + radius -> ids ================
#pragma unroll
    for (int t = 0; t < KNN; ++t) SLOT(uS, t, tid) = keys[t];
    __syncthreads();
    if (wv < 8) {
#pragma unroll
        for (int t = 0; t < KNN; ++t) merge_one(keys, SLOT(uS, t, tid + 512));
#pragma unroll
        for (int t = 0; t < KNN; ++t) SLOT(uS, t, tid) = keys[t];
    }
    __syncthreads();
    if (wv < 4) {
#pragma unroll
        for (int t = 0; t < KNN; ++t) merge_one(keys, SLOT(uS, t, tid + 256));
#pragma unroll
        for (int t = 0; t < KNN; ++t) SLOT(uS, t, tid) = keys[t];
    }
    __syncthreads();
    if (wv < 2) {
#pragma unroll
        for (int t = 0; t < KNN; ++t) merge_one(keys, SLOT(uS, t, tid + 128));
#pragma unroll
        for (int t = 0; t < KNN; ++t) SLOT(uS, t, tid) = keys[t];
    }
    __syncthreads();
    if (wv == 0) {
#pragma unroll
        for (int t = 0; t < KNN; ++t) merge_one(keys, SLOT(uS, t, tid + 64));
        const int id0 = (int)(keys[0] & 0x3FFFu);   // nearest (self)
#pragma unroll
        for (int t = 0; t < KNN; ++t) {
            float d2t = __uint_as_float(keys[t] & 0xFFFFC000u);
            int   j   = (int)(keys[t] & 0x3FFFu);
            SLOT(uS, t, lane) = (unsigned)((d2t > 1.0f) ? id0 : j);
        }
    }
    __syncthreads();

    // ================= Phase C: loss + reduce + finalize ==================
    {
        const int s  = wv & 7;
        const int kh = wv >> 3;
        const float* fs = flow + (size_t)s * NPTS * 3;
        const float fx = fs[3 * i + 0];
        const float fy = fs[3 * i + 1];
        const float fz = fs[3 * i + 2];

        float sum = 0.0f;
#pragma unroll
        for (int z = 0; z < 8; ++z) {
            int j = (int)SLOT(uS, kh * 8 + z, lane);   // conflict-free
            float dx = fx - fs[3 * j + 0];
            float dy = fy - fs[3 * j + 1];
            float dz = fz - fs[3 * j + 2];
            float sq = fmaf(dx, dx, fmaf(dy, dy, dz * dz));
            sum += (sq > 0.0f) ? sqrtf(sq) : 0.0f;
        }

        float contrib = wts[i] * sum;
#pragma unroll
        for (int off = 32; off > 0; off >>= 1) contrib += __shfl_down(contrib, off);
        if (lane == 0) sred[wv] = contrib;

        if (wv == 0) {                       // weight sum, once per block
            float wi = wts[i];
#pragma unroll
            for (int off = 32; off > 0; off >>= 1) wi += __shfl_down(wi, off);
            if (lane == 0) atomicAdd(&accum[1], wi);
        }
        __syncthreads();

        if (tid == 0) {
            float c = 0.0f;
#pragma unroll
            for (int t = 0; t < NW; ++t) c += sred[t];
            atomicAdd(&accum[0], c);
            __threadfence();
            unsigned ticket = atomicAdd((unsigned*)&accum[2], 1u);
            if (ticket == gridDim.x - 1) {   // last block finalizes
                float a  = atomicAdd(&accum[0], 0.0f);   // coherent read
                float ws = atomicAdd(&accum[1], 0.0f);
                float v  = a / (float)(KNN * SEQV);
                out[0] = (ws > 0.0f) ? (v / ws) : v;
            }
        }
    }
}

extern "C" void kernel_launch(void* const* d_in, const int* in_sizes, int n_in,
                              void* d_out, int out_size, void* d_ws, size_t ws_size,
                              hipStream_t stream)
{
    const float* pc   = (const float*)d_in[0];   // (1, N, 3)
    const float* flow = (const float*)d_in[1];   // (SEQ, N, 3)
    const float* wts  = (const float*)d_in[2];   // (N,)
    float* out = (float*)d_out;

    // layout: accum(256 B) | pc4(256 KB)
    float*  accum = (float*)d_ws;
    float4* pc4   = (float4*)((char*)d_ws + 256);

    pack_kernel<<<NPTS / 256, 256, 0, stream>>>(pc, pc4, accum);
    mega_kernel<<<NPTS / 64, 1024, 0, stream>>>(pc4, flow, wts, accum, out);
}

// Round 2
// 238.301 us; speedup vs baseline: 1.8092x; 1.8092x over previous
//
#include <hip/hip_runtime.h>
#include <math.h>

#define NPTS  16384
#define KNN   16
#define SEQV  8
#define NW    16      // waves per block
#define SLICE 1024    // candidates per wave slice
#define BATCH 8
#define CAPM  15      // append words/thread (flush thr 7 -> max idx 14, storm-free)
#define RSAMP 256     // tau subsample per wave -> 4096-sample per query
#define COLD  16      // unconditional seed merges (guarantees keys[15] valid)

// Transposed LDS slot: row t (0..15), column col (0..1023).
// bank = col mod 32 -> consecutive lanes = consecutive banks = conflict-free.
#define SLOT(arr, t, col) arr[(t) * 1024 + (col)]

__device__ __forceinline__ unsigned umin_(unsigned a, unsigned b) { return a < b ? a : b; }
__device__ __forceinline__ unsigned umax_(unsigned a, unsigned b) { return a > b ? a : b; }

// merge one key into sorted ascending keys[16]
__device__ __forceinline__ void merge_one(unsigned keys[KNN], unsigned kk) {
    if (kk < keys[KNN - 1]) {
#pragma unroll
        for (int u = 0; u < KNN; ++u) {
            unsigned lo = umin_(kk, keys[u]);
            kk = umax_(kk, keys[u]);
            keys[u] = lo;
        }
    }
}

// ---------------------------------------------------------------------------
// K0: pack pc4[i] = (-2x, -2y, -2z, |c|^2); zero accumulators.
//   d2p = d2 - |q|^2 = m.x*qx + m.y*qy + m.z*qz + m.w  (pure 3-fma chain)
// Query recovered bit-exactly as q = -0.5 * m (power-of-2 scale).
// ---------------------------------------------------------------------------
__global__ __launch_bounds__(256) void pack_kernel(
    const float* __restrict__ pc, float4* __restrict__ pc4,
    float* __restrict__ accum)
{
    const int i = blockIdx.x * 256 + threadIdx.x;
    if (i == 0) {
        accum[0] = 0.0f; accum[1] = 0.0f;
        ((unsigned*)accum)[2] = 0u; ((unsigned*)accum)[3] = 0u;
    }
    const float x = pc[3 * i + 0];
    const float y = pc[3 * i + 1];
    const float z = pc[3 * i + 2];
    const float w = fmaf(x, x, fmaf(y, y, z * z));
    pc4[i] = make_float4(-2.0f * x, -2.0f * y, -2.0f * z, w);
}

// ---------------------------------------------------------------------------
// K1: fused tau + scan + loss. Grid 256 x 1024, 64 queries/block (lane =
// query), 16 waves each own a 1024-candidate slice.
//
// Tau phase: wave scans first RSAMP=256 of its slice (4096-sample/query):
//   COLD=16 unconditional merges seed keys, then filtered scan at
//   tau0 = 8 * analytic d16^2 (points ~ N(0,1)^3 => d16^2 ~ 0.0238*e^(q2/3);
//   E[predicated merges] ~ 6/lane, wave-rare flushes). Tree merge -> EXACT
//   4096-sample d16. Certificate: margined d16 <= tau0 proves completeness
//   of the filtered scan (else tau = 3e38, correct-but-slow; P ~ 1e-7).
// Phase A: full-slice filtered scan at margined sample-d16 (E[accepts]=4).
// Phase B/C: tree merge + radius + loss (verbatim from the 108us kernel).
// key = (d2 bits & 0xFFFFC000) | j  (j < 2^14).
// accum[0]=loss, accum[1]=wsum, accum[2]=ticket (zeroed by K0).
// ---------------------------------------------------------------------------
__global__ __launch_bounds__(1024, 4) void mega_kernel(
    const float4* __restrict__ pc4, const float* __restrict__ flow,
    const float* __restrict__ wts, float* __restrict__ accum,
    float* __restrict__ out)
{
    __shared__ unsigned uS[1024 * 16];   // 64 KB union: scan bufs / merge / ids
    float* sred = (float*)&uS[15 * 1024 + 1000];
    // tau broadcast: words 16320..16383 (row15 cols 960+). Live only between
    // tree-1 final and Phase-A start; bufs never touch words >= 15360.
    float* sTau = (float*)&uS[16320];

    const int tid  = threadIdx.x;
    const int lane = tid & 63;
    const int wv   = __builtin_amdgcn_readfirstlane(tid >> 6);   // 0..15
    const int i    = blockIdx.x * 64 + lane;

    const float4 mi = pc4[i];
    const float qx = -0.5f * mi.x;      // exact: power-of-2 rescale
    const float qy = -0.5f * mi.y;
    const float qz = -0.5f * mi.z;
    const float q2 = mi.w;

    // analytic tau0 = 8 * expected d16^2 for N(0,1)^3, N=16384:
    //   d16^2 ~ 0.02384 * exp(q2/3);  8x safety => cert-fail P ~ 1e-7
    const float tau0 = 0.19072f * exp2f(0.480898f * q2);   // d2 space

    unsigned keys[KNN];
#pragma unroll
    for (int t = 0; t < KNN; ++t) keys[t] = 0xFFFFFFFFu;
    int cnt = 0;
    unsigned* buf = &uS[tid * CAPM];     // stride 15 (odd) -> spread banks

    const int jbeg = wv * SLICE;
    const float4* cb = pc4 + jbeg;       // wave-uniform -> s_load bursts

    // ================= Tau phase: filtered 256-subsample scan =============
    {
        float4 A[BATCH], B[BATCH];
        // --- cold seed: first 16 candidates, unconditional merges ---
#pragma unroll
        for (int q = 0; q < BATCH; ++q) A[q] = cb[q];
#pragma unroll
        for (int q = 0; q < BATCH; ++q) B[q] = cb[BATCH + q];
#pragma unroll
        for (int q = 0; q < BATCH; ++q) {
            const float4 c = A[q];
            float d2p = fmaf(c.x, qx, fmaf(c.y, qy, fmaf(c.z, qz, c.w)));
            float d2  = fmaxf(d2p + q2, 0.0f);
            merge_one(keys, (__float_as_uint(d2) & 0xFFFFC000u)
                          | (unsigned)(jbeg + q));
        }
#pragma unroll
        for (int q = 0; q < BATCH; ++q) {
            const float4 c = B[q];
            float d2p = fmaf(c.x, qx, fmaf(c.y, qy, fmaf(c.z, qz, c.w)));
            float d2  = fmaxf(d2p + q2, 0.0f);
            merge_one(keys, (__float_as_uint(d2) & 0xFFFFC000u)
                          | (unsigned)(jbeg + BATCH + q));
        }
        // keys[15] now real -> tighten threshold (d2p space)
        float t0p;
        {
            float d16c = __uint_as_float(keys[KNN - 1] & 0xFFFFC000u);
            t0p = fminf(tau0, fmaf(d16c, 1.0002f, 1e-6f)) - q2;
        }

        auto procT = [&](const float4* C, int jbase) {
#pragma unroll
            for (int q = 0; q < BATCH; ++q) {
                const float4 c = C[q];
                float d2p = fmaf(c.x, qx, fmaf(c.y, qy, fmaf(c.z, qz, c.w)));
                if (d2p <= t0p) {                      // exec-masked accept
                    float d2 = fmaxf(d2p + q2, 0.0f);
                    buf[cnt] = (__float_as_uint(d2) & 0xFFFFC000u)
                             | (unsigned)(jbeg + jbase + q);
                    ++cnt;
                }
            }
            if (cnt >= CAPM - BATCH) {
#pragma unroll 1
                for (int t = 0; t < cnt; ++t) merge_one(keys, buf[t]);
                cnt = 0;
                float d16n = __uint_as_float(keys[KNN - 1] & 0xFFFFC000u);
                t0p = fminf(t0p, fmaf(d16n, 1.0002f, 1e-6f) - q2);
            }
        };

#pragma unroll
        for (int q = 0; q < BATCH; ++q) A[q] = cb[COLD + q];
#pragma unroll 1
        for (int jo = COLD; jo < RSAMP; jo += 2 * BATCH) {
#pragma unroll
            for (int q = 0; q < BATCH; ++q) B[q] = cb[jo + BATCH + q];
            procT(A, jo);
            if (jo + 2 * BATCH < RSAMP) {
#pragma unroll
                for (int q = 0; q < BATCH; ++q) A[q] = cb[jo + 2 * BATCH + q];
            }
            procT(B, jo + BATCH);
        }
#pragma unroll 1
        for (int t = 0; t < cnt; ++t) merge_one(keys, buf[t]);
    }
    __syncthreads();   // scan bufs dead; reuse uS as transposed merge slots

    // ================= Tree merge 1 -> exact 4096-sample tau ==============
#pragma unroll
    for (int t = 0; t < KNN; ++t) SLOT(uS, t, tid) = keys[t];
    __syncthreads();
    if (wv < 8) {
#pragma unroll
        for (int t = 0; t < KNN; ++t) merge_one(keys, SLOT(uS, t, tid + 512));
#pragma unroll
        for (int t = 0; t < KNN; ++t) SLOT(uS, t, tid) = keys[t];
    }
    __syncthreads();
    if (wv < 4) {
#pragma unroll
        for (int t = 0; t < KNN; ++t) merge_one(keys, SLOT(uS, t, tid + 256));
#pragma unroll
        for (int t = 0; t < KNN; ++t) SLOT(uS, t, tid) = keys[t];
    }
    __syncthreads();
    if (wv < 2) {
#pragma unroll
        for (int t = 0; t < KNN; ++t) merge_one(keys, SLOT(uS, t, tid + 128));
#pragma unroll
        for (int t = 0; t < KNN; ++t) SLOT(uS, t, tid) = keys[t];
    }
    __syncthreads();
    if (wv == 0) {
#pragma unroll
        for (int t = 0; t < KNN; ++t) merge_one(keys, SLOT(uS, t, tid + 64));
        const float d16 = __uint_as_float(keys[KNN - 1] & 0xFFFFC000u);
        const float tf  = fmaf(d16, 1.0002f, 1e-6f);
        // certificate: margined d16 within the tau0 scan window proves the
        // filtered subsample scan was complete. NaN (sentinel) fails the
        // compare -> fallback. Fallback is correct-but-slow, P ~ 1e-7.
        sTau[lane] = (tf <= tau0) ? tf : 3.0e38f;
    }
    __syncthreads();

    // ================= Phase A: filtered full-slice scan ==================
    float tauf = sTau[lane] - q2;        // d2p-space threshold
#pragma unroll
    for (int t = 0; t < KNN; ++t) keys[t] = 0xFFFFFFFFu;
    cnt = 0;
    {
        float4 A[BATCH], B[BATCH];
#pragma unroll
        for (int q = 0; q < BATCH; ++q) A[q] = cb[q];

        auto process = [&](const float4* C, int jbase) {
#pragma unroll
            for (int q = 0; q < BATCH; ++q) {
                const float4 c = C[q];
                float d2p = fmaf(c.x, qx, fmaf(c.y, qy, fmaf(c.z, qz, c.w)));
                if (d2p <= tauf) {                     // exec-masked accept
                    float d2 = fmaxf(d2p + q2, 0.0f);
                    buf[cnt] = (__float_as_uint(d2) & 0xFFFFC000u)
                             | (unsigned)(jbeg + jbase + q);
                    ++cnt;
                }
            }
            // headroom: enter batch with cnt <= 6 -> max idx 14 = CAPM-1
            if (cnt >= CAPM - BATCH) {
#pragma unroll 1
                for (int t = 0; t < cnt; ++t) merge_one(keys, buf[t]);
                cnt = 0;
                float d16n = __uint_as_float(keys[KNN - 1] & 0xFFFFC000u);
                tauf = fminf(tauf, fmaf(d16n, 1.0002f, 1e-6f) - q2);
            }
        };

#pragma unroll 1
        for (int jo = 0; jo < SLICE; jo += 2 * BATCH) {
#pragma unroll
            for (int q = 0; q < BATCH; ++q) B[q] = cb[jo + BATCH + q];
            process(A, jo);
            if (jo + 2 * BATCH < SLICE) {
#pragma unroll
                for (int q = 0; q < BATCH; ++q) A[q] = cb[jo + 2 * BATCH + q];
            }
            process(B, jo + BATCH);
        }
#pragma unroll 1
        for (int t = 0; t < cnt; ++t) merge_one(keys, buf[t]);
    }
    __syncthreads();   // scan buffers dead; reuse uS as transposed merge slots

    // ================= Phase B: tree merge + radius -> ids ================
#pragma unroll
    for (int t = 0; t < KNN; ++t) SLOT(uS, t, tid) = keys[t];
    __syncthreads();
    if (wv < 8) {
#pragma unroll
        for (int t = 0; t < KNN; ++t) merge_one(keys, SLOT(uS, t, tid + 512));
#pragma unroll
        for (int t = 0; t < KNN; ++t) SLOT(uS, t, tid) = keys[t];
    }
    __syncthreads();
    if (wv < 4) {
#pragma unroll
        for (int t = 0; t < KNN; ++t) merge_one(keys, SLOT(uS, t, tid + 256));
#pragma unroll
        for (int t = 0; t < KNN; ++t) SLOT(uS, t, tid) = keys[t];
    }
    __syncthreads();
    if (wv < 2) {
#pragma unroll
        for (int t = 0; t < KNN; ++t) merge_one(keys, SLOT(uS, t, tid + 128));
#pragma unroll
        for (int t = 0; t < KNN; ++t) SLOT(uS, t, tid) = keys[t];
    }
    __syncthreads();
    if (wv == 0) {
#pragma unroll
        for (int t = 0; t < KNN; ++t) merge_one(keys, SLOT(uS, t, tid + 64));
        const int id0 = (int)(keys[0] & 0x3FFFu);   // nearest (self)
#pragma unroll
        for (int t = 0; t < KNN; ++t) {
            float d2t = __uint_as_float(keys[t] & 0xFFFFC000u);
            int   j   = (int)(keys[t] & 0x3FFFu);
            SLOT(uS, t, lane) = (unsigned)((d2t > 1.0f) ? id0 : j);
        }
    }
    __syncthreads();

    // ================= Phase C: loss + reduce + finalize ==================
    {
        const int s  = wv & 7;
        const int kh = wv >> 3;
        const float* fs = flow + (size_t)s * NPTS * 3;
        const float fx = fs[3 * i + 0];
        const float fy = fs[3 * i + 1];
        const float fz = fs[3 * i + 2];

        float sum = 0.0f;
#pragma unroll
        for (int z = 0; z < 8; ++z) {
            int j = (int)SLOT(uS, kh * 8 + z, lane);   // conflict-free
            float dx = fx - fs[3 * j + 0];
            float dy = fy - fs[3 * j + 1];
            float dz = fz - fs[3 * j + 2];
            float sq = fmaf(dx, dx, fmaf(dy, dy, dz * dz));
            sum += (sq > 0.0f) ? sqrtf(sq) : 0.0f;
        }

        float contrib = wts[i] * sum;
#pragma unroll
        for (int off = 32; off > 0; off >>= 1) contrib += __shfl_down(contrib, off);
        if (lane == 0) sred[wv] = contrib;

        if (wv == 0) {                       // weight sum, once per block
            float wi = wts[i];
#pragma unroll
            for (int off = 32; off > 0; off >>= 1) wi += __shfl_down(wi, off);
            if (lane == 0) atomicAdd(&accum[1], wi);
        }
        __syncthreads();

        if (tid == 0) {
            float c = 0.0f;
#pragma unroll
            for (int t = 0; t < NW; ++t) c += sred[t];
            atomicAdd(&accum[0], c);
            __threadfence();
            unsigned ticket = atomicAdd((unsigned*)&accum[2], 1u);
            if (ticket == gridDim.x - 1) {   // last block finalizes
                float a  = atomicAdd(&accum[0], 0.0f);   // coherent read
                float ws = atomicAdd(&accum[1], 0.0f);
                float v  = a / (float)(KNN * SEQV);
                out[0] = (ws > 0.0f) ? (v / ws) : v;
            }
        }
    }
}

extern "C" void kernel_launch(void* const* d_in, const int* in_sizes, int n_in,
                              void* d_out, int out_size, void* d_ws, size_t ws_size,
                              hipStream_t stream)
{
    const float* pc   = (const float*)d_in[0];   // (1, N, 3)
    const float* flow = (const float*)d_in[1];   // (SEQ, N, 3)
    const float* wts  = (const float*)d_in[2];   // (N,)
    float* out = (float*)d_out;

    // layout: accum(256 B) | pc4(256 KB)
    float*  accum = (float*)d_ws;
    float4* pc4   = (float4*)((char*)d_ws + 256);

    pack_kernel<<<NPTS / 256, 256, 0, stream>>>(pc, pc4, accum);
    mega_kernel<<<NPTS / 64, 1024, 0, stream>>>(pc4, flow, wts, accum, out);
}

// Round 3
// 163.944 us; speedup vs baseline: 2.6298x; 1.4536x over previous
//
#include <hip/hip_runtime.h>
#include <math.h>

#define NPTS  16384
#define KNN   16
#define SEQV  8
#define NW    16      // waves per block
#define SLICE 1024    // candidates per wave slice
#define BATCH 8
#define CAPM  15      // append words/thread (odd stride spreads banks)
#define RSAMP 256     // tau subsample per wave -> 4096-sample per query
#define CAPR  1.001f  // radius cap in d2 space: neighbors with d2>1 map to
                      // self (loss 0), so tau never needs to exceed ~1.

// Transposed LDS slot: row t (0..15), column col (0..1023).
// bank = col mod 32 -> consecutive lanes = consecutive banks = conflict-free.
#define SLOT(arr, t, col) arr[(t) * 1024 + (col)]

__device__ __forceinline__ unsigned umin_(unsigned a, unsigned b) { return a < b ? a : b; }
__device__ __forceinline__ unsigned umax_(unsigned a, unsigned b) { return a > b ? a : b; }

// merge one key into sorted ascending keys[16] (scan-path flushes only)
__device__ __forceinline__ void merge_one(unsigned keys[KNN], unsigned kk) {
    if (kk < keys[KNN - 1]) {
#pragma unroll
        for (int u = 0; u < KNN; ++u) {
            unsigned lo = umin_(kk, keys[u]);
            kk = umax_(kk, keys[u]);
            keys[u] = lo;
        }
    }
}

// Exact top-16 of two sorted-ascending 16-lists: bitonic half-clean (16 min)
// + 4-stage static sort network (64 ops). ~80 unpredicated VALU vs ~528 for
// 16 predicated merge_one chains. Used for all tree-merge levels.
__device__ __forceinline__ void merge16(unsigned k[KNN], const unsigned o[KNN]) {
    unsigned v[KNN];
#pragma unroll
    for (int i = 0; i < KNN; ++i) v[i] = umin_(k[i], o[KNN - 1 - i]);
    // v is bitonic; sort ascending with half-cleaner stages 8,4,2,1
#pragma unroll
    for (int d = 8; d >= 1; d >>= 1) {
#pragma unroll
        for (int i = 0; i < KNN; ++i) {
            if ((i & d) == 0) {
                unsigned lo = umin_(v[i], v[i + d]);
                unsigned hi = umax_(v[i], v[i + d]);
                v[i] = lo; v[i + d] = hi;
            }
        }
    }
#pragma unroll
    for (int i = 0; i < KNN; ++i) k[i] = v[i];
}

__device__ __forceinline__ void tree_load_merge(unsigned* uS, unsigned keys[KNN], int src) {
    unsigned o[KNN];
#pragma unroll
    for (int t = 0; t < KNN; ++t) o[t] = SLOT(uS, t, src);
    merge16(keys, o);
}

// ---------------------------------------------------------------------------
// Single fused kernel. Grid 256 x 1024; block owns 64 queries (lane = query),
// wave wv scans candidate slice [1024*wv, 1024*(wv+1)).
// Reads raw pc (wave-uniform candidate loads -> s_load; dx-form distance
// needs no |c|^2, so no pack kernel / pc4 / inter-kernel gap).
//
// Tau phase: filtered scan of first RSAMP=256 slice cands at
//   tau0 = min(8x analytic d16^2, CAPR); tree merge -> exact 4096-sample d16.
//   Certificate: margined d16 <= tau0 proves sample completeness; else tau =
//   CAPR (radius cap), which is ALWAYS sufficient since d2>1 neighbors map to
//   self (zero loss). Analytic constant is perf-only, never correctness.
// Phase A: full-slice filtered scan, wave-branched accepts (__any).
// Phase B/C: tree merge + radius + loss (validated machinery, unchanged).
// key = (d2 bits & 0xFFFFC000) | j  (j < 2^14).
// accum[0]=loss, accum[1]=wsum, accum[2]=ticket (zeroed by hipMemsetAsync).
// ---------------------------------------------------------------------------
__global__ __launch_bounds__(1024, 4) void mega_kernel(
    const float* __restrict__ pc, const float* __restrict__ flow,
    const float* __restrict__ wts, float* __restrict__ accum,
    float* __restrict__ out)
{
    __shared__ unsigned uS[1024 * 16];   // 64 KB union: scan bufs / merge / ids
    float* sred = (float*)&uS[15 * 1024 + 1000];
    // tau broadcast: words 16320..16383 (row15 cols 960+); bufs stay <15360.
    float* sTau = (float*)&uS[16320];

    const int tid  = threadIdx.x;
    const int lane = tid & 63;
    const int wv   = __builtin_amdgcn_readfirstlane(tid >> 6);   // 0..15
    const int i    = blockIdx.x * 64 + lane;

    const float qx = pc[3 * i + 0];
    const float qy = pc[3 * i + 1];
    const float qz = pc[3 * i + 2];
    const float q2 = fmaf(qx, qx, fmaf(qy, qy, qz * qz));

    // 8x analytic E[d16^2] for N(0,1)^3, N=16384: 0.19072*e^(q2/3), capped.
    const float tau0 = fminf(0.19072f * exp2f(0.480898f * q2), CAPR);

    unsigned keys[KNN];
#pragma unroll
    for (int t = 0; t < KNN; ++t) keys[t] = 0xFFFFFFFFu;
    int cnt = 0;
    unsigned* buf = &uS[tid * CAPM];     // stride 15 (odd) -> spread banks

    const int jbeg = wv * SLICE;
    const float* cb = pc + 3 * (size_t)jbeg;   // wave-uniform -> s_load

    float A[3 * BATCH], B[3 * BATCH];

    // ================= Tau phase: filtered RSAMP-subsample scan ===========
    {
        float tauT = tau0;
        auto procT = [&](const float* C, int jbase) {
#pragma unroll
            for (int q = 0; q < BATCH; ++q) {
                float dx = qx - C[3 * q + 0];
                float dy = qy - C[3 * q + 1];
                float dz = qz - C[3 * q + 2];
                float d2 = fmaf(dx, dx, fmaf(dy, dy, dz * dz));
                bool acc = d2 <= tauT;
                if (__any(acc)) {                    // wave-rare branch
                    if (acc) {
                        buf[cnt] = (__float_as_uint(d2) & 0xFFFFC000u)
                                 | (unsigned)(jbeg + jbase + q);
                        ++cnt;
                    }
                    if (cnt >= CAPM - 1) {           // execz-skipped flush
#pragma unroll 1
                        for (int t = 0; t < cnt; ++t) merge_one(keys, buf[t]);
                        cnt = 0;
                        // sentinel keys[15] -> NaN -> fminf keeps old tauT
                        float d16n = __uint_as_float(keys[KNN - 1] & 0xFFFFC000u);
                        tauT = fminf(tauT, fmaf(d16n, 1.0002f, 1e-6f));
                    }
                }
            }
        };

#pragma unroll
        for (int u = 0; u < 3 * BATCH; ++u) A[u] = cb[u];
#pragma unroll 1
        for (int jo = 0; jo < RSAMP; jo += 2 * BATCH) {
#pragma unroll
            for (int u = 0; u < 3 * BATCH; ++u) B[u] = cb[3 * (jo + BATCH) + u];
            procT(A, jo);
            if (jo + 2 * BATCH < RSAMP) {
#pragma unroll
                for (int u = 0; u < 3 * BATCH; ++u) A[u] = cb[3 * (jo + 2 * BATCH) + u];
            }
            procT(B, jo + BATCH);
        }
#pragma unroll 1
        for (int t = 0; t < cnt; ++t) merge_one(keys, buf[t]);
        cnt = 0;
    }
    __syncthreads();   // scan bufs dead; reuse uS as transposed merge slots

    // ================= Tree merge 1 -> exact 4096-sample tau ==============
#pragma unroll
    for (int t = 0; t < KNN; ++t) SLOT(uS, t, tid) = keys[t];
    __syncthreads();
    if (wv < 8) {
        tree_load_merge(uS, keys, tid + 512);
#pragma unroll
        for (int t = 0; t < KNN; ++t) SLOT(uS, t, tid) = keys[t];
    }
    __syncthreads();
    if (wv < 4) {
        tree_load_merge(uS, keys, tid + 256);
#pragma unroll
        for (int t = 0; t < KNN; ++t) SLOT(uS, t, tid) = keys[t];
    }
    __syncthreads();
    if (wv < 2) {
        tree_load_merge(uS, keys, tid + 128);
#pragma unroll
        for (int t = 0; t < KNN; ++t) SLOT(uS, t, tid) = keys[t];
    }
    __syncthreads();
    if (wv == 0) {
        tree_load_merge(uS, keys, tid + 64);
        const float d16 = __uint_as_float(keys[KNN - 1] & 0xFFFFC000u);
        const float tf  = fmaf(d16, 1.0002f, 1e-6f);
        // cert pass -> sample tau; fail (incl. NaN sentinel) -> radius cap,
        // which is always correctness-sufficient.
        sTau[lane] = (tf <= tau0) ? tf : CAPR;
    }
    __syncthreads();

    // ================= Phase A: filtered full-slice scan ==================
    float tauf = sTau[lane];             // d2-space threshold
#pragma unroll
    for (int t = 0; t < KNN; ++t) keys[t] = 0xFFFFFFFFu;
    {
        auto process = [&](const float* C, int jbase) {
#pragma unroll
            for (int q = 0; q < BATCH; ++q) {
                float dx = qx - C[3 * q + 0];
                float dy = qy - C[3 * q + 1];
                float dz = qz - C[3 * q + 2];
                float d2 = fmaf(dx, dx, fmaf(dy, dy, dz * dz));
                bool acc = d2 <= tauf;
                if (__any(acc)) {                    // wave-rare branch
                    if (acc) {
                        buf[cnt] = (__float_as_uint(d2) & 0xFFFFC000u)
                                 | (unsigned)(jbeg + jbase + q);
                        ++cnt;
                    }
                    if (cnt >= CAPM - 1) {           // execz-skipped flush
#pragma unroll 1
                        for (int t = 0; t < cnt; ++t) merge_one(keys, buf[t]);
                        cnt = 0;
                        float d16n = __uint_as_float(keys[KNN - 1] & 0xFFFFC000u);
                        tauf = fminf(tauf, fmaf(d16n, 1.0002f, 1e-6f));
                    }
                }
            }
        };

#pragma unroll
        for (int u = 0; u < 3 * BATCH; ++u) A[u] = cb[u];
#pragma unroll 1
        for (int jo = 0; jo < SLICE; jo += 2 * BATCH) {
#pragma unroll
            for (int u = 0; u < 3 * BATCH; ++u) B[u] = cb[3 * (jo + BATCH) + u];
            process(A, jo);
            if (jo + 2 * BATCH < SLICE) {
#pragma unroll
                for (int u = 0; u < 3 * BATCH; ++u) A[u] = cb[3 * (jo + 2 * BATCH) + u];
            }
            process(B, jo + BATCH);
        }
#pragma unroll 1
        for (int t = 0; t < cnt; ++t) merge_one(keys, buf[t]);
    }
    __syncthreads();   // scan buffers dead; reuse uS for tree 2

    // ================= Phase B: tree merge + radius -> ids ================
#pragma unroll
    for (int t = 0; t < KNN; ++t) SLOT(uS, t, tid) = keys[t];
    __syncthreads();
    if (wv < 8) {
        tree_load_merge(uS, keys, tid + 512);
#pragma unroll
        for (int t = 0; t < KNN; ++t) SLOT(uS, t, tid) = keys[t];
    }
    __syncthreads();
    if (wv < 4) {
        tree_load_merge(uS, keys, tid + 256);
#pragma unroll
        for (int t = 0; t < KNN; ++t) SLOT(uS, t, tid) = keys[t];
    }
    __syncthreads();
    if (wv < 2) {
        tree_load_merge(uS, keys, tid + 128);
#pragma unroll
        for (int t = 0; t < KNN; ++t) SLOT(uS, t, tid) = keys[t];
    }
    __syncthreads();
    if (wv == 0) {
        tree_load_merge(uS, keys, tid + 64);
        const int id0 = (int)(keys[0] & 0x3FFFu);   // nearest (self)
#pragma unroll
        for (int t = 0; t < KNN; ++t) {
            float d2t = __uint_as_float(keys[t] & 0xFFFFC000u);
            int   j   = (int)(keys[t] & 0x3FFFu);
            SLOT(uS, t, lane) = (unsigned)((d2t > 1.0f) ? id0 : j);
        }
    }
    __syncthreads();

    // ================= Phase C: loss + reduce + finalize ==================
    {
        const int s  = wv & 7;
        const int kh = wv >> 3;
        const float* fs = flow + (size_t)s * NPTS * 3;
        const float fx = fs[3 * i + 0];
        const float fy = fs[3 * i + 1];
        const float fz = fs[3 * i + 2];

        float sum = 0.0f;
#pragma unroll
        for (int z = 0; z < 8; ++z) {
            int j = (int)SLOT(uS, kh * 8 + z, lane);   // conflict-free
            float dx = fx - fs[3 * j + 0];
            float dy = fy - fs[3 * j + 1];
            float dz = fz - fs[3 * j + 2];
            float sq = fmaf(dx, dx, fmaf(dy, dy, dz * dz));
            sum += (sq > 0.0f) ? sqrtf(sq) : 0.0f;
        }

        float contrib = wts[i] * sum;
#pragma unroll
        for (int off = 32; off > 0; off >>= 1) contrib += __shfl_down(contrib, off);
        if (lane == 0) sred[wv] = contrib;

        if (wv == 0) {                       // weight sum, once per block
            float wi = wts[i];
#pragma unroll
            for (int off = 32; off > 0; off >>= 1) wi += __shfl_down(wi, off);
            if (lane == 0) atomicAdd(&accum[1], wi);
        }
        __syncthreads();

        if (tid == 0) {
            float c = 0.0f;
#pragma unroll
            for (int t = 0; t < NW; ++t) c += sred[t];
            atomicAdd(&accum[0], c);
            __threadfence();
            unsigned ticket = atomicAdd((unsigned*)&accum[2], 1u);
            if (ticket == gridDim.x - 1) {   // last block finalizes
                float a  = atomicAdd(&accum[0], 0.0f);   // coherent read
                float ws = atomicAdd(&accum[1], 0.0f);
                float v  = a / (float)(KNN * SEQV);
                out[0] = (ws > 0.0f) ? (v / ws) : v;
            }
        }
    }
}

extern "C" void kernel_launch(void* const* d_in, const int* in_sizes, int n_in,
                              void* d_out, int out_size, void* d_ws, size_t ws_size,
                              hipStream_t stream)
{
    const float* pc   = (const float*)d_in[0];   // (1, N, 3)
    const float* flow = (const float*)d_in[1];   // (SEQ, N, 3)
    const float* wts  = (const float*)d_in[2];   // (N,)
    float* out = (float*)d_out;

    float* accum = (float*)d_ws;                 // accum[0..3]
    hipMemsetAsync(d_ws, 0, 32, stream);         // loss/wsum/ticket = 0

    mega_kernel<<<NPTS / 64, 1024, 0, stream>>>(pc, flow, wts, accum, out);
}